// Round 6
// baseline (286.351 us; speedup 1.0000x reference)
//
#include <hip/hip_runtime.h>

typedef unsigned short u16;
typedef __attribute__((ext_vector_type(8))) short bf16x8;
typedef __attribute__((ext_vector_type(4))) float f32x4;
typedef __attribute__((ext_vector_type(16))) float f32x16;

#define MFMA(a, b, c) __builtin_amdgcn_mfma_f32_16x16x32_bf16(a, b, c, 0, 0, 0)
#define MFMA32(a, b, c) __builtin_amdgcn_mfma_f32_32x32x16_bf16(a, b, c, 0, 0, 0)

// 2^x. clang builtin lowers to v_exp_f32 with compiler-managed TRANS hazards.
#if defined(__has_builtin)
#if __has_builtin(__builtin_amdgcn_exp2f)
#define EXP2(x) __builtin_amdgcn_exp2f(x)
#endif
#endif
#ifndef EXP2
#define EXP2(x) exp2f(x)
#endif

// async global->LDS, 16B per lane; lds ptr must be wave-uniform base.
#define ASYNC16(g, l)                                                      \
  __builtin_amdgcn_global_load_lds(                                        \
      (const __attribute__((address_space(1))) void*)(g),                  \
      (__attribute__((address_space(3))) void*)(l), 16, 0, 0)

__device__ __forceinline__ u16 f2bf(float x) {
  union { float f; unsigned u; } v; v.f = x;
  unsigned r = (v.u + 0x7fffu + ((v.u >> 16) & 1u)) >> 16;
  return (u16)r;
}

// pack two f32 -> bf16x2 (round-half-up), plain VALU ops (hazard-visible)
__device__ __forceinline__ unsigned pack_bf2(float a, float b) {
  unsigned ua = __float_as_uint(a) + 0x8000u;
  unsigned ub = __float_as_uint(b) + 0x8000u;
  return __builtin_amdgcn_perm(ub, ua, 0x07060302u);
}

// exp2 + pack 8 consecutive regs (B..B+7) of an f32x16 into one bf16x8
#define EXP_PACK8(s, B)                                         \
  ({                                                            \
    union { unsigned u[4]; bf16x8 v; } r_;                      \
    r_.u[0] = pack_bf2(EXP2((s)[(B) + 0]), EXP2((s)[(B) + 1])); \
    r_.u[1] = pack_bf2(EXP2((s)[(B) + 2]), EXP2((s)[(B) + 3])); \
    r_.u[2] = pack_bf2(EXP2((s)[(B) + 4]), EXP2((s)[(B) + 5])); \
    r_.u[3] = pack_bf2(EXP2((s)[(B) + 6]), EXP2((s)[(B) + 7])); \
    r_.v;                                                       \
  })

// ---------------- transpose + fp32->bf16 (w_in, w_out) ----------------
__global__ void transpose_to_bf16(const float* __restrict__ in, u16* __restrict__ out,
                                  int R, int C) {
  __shared__ float tile[32][33];
  int c0 = blockIdx.x * 32, r0 = blockIdx.y * 32;
  int tx = threadIdx.x, ty = threadIdx.y;  // 32 x 8
#pragma unroll
  for (int i = 0; i < 32; i += 8)
    tile[ty + i][tx] = in[(size_t)(r0 + ty + i) * C + c0 + tx];
  __syncthreads();
#pragma unroll
  for (int i = 0; i < 32; i += 8)
    out[(size_t)(c0 + ty + i) * R + r0 + tx] = f2bf(tile[tx][ty + i]);
}

// ---------------- fp32 -> bf16 (x) ----------------
__global__ void f32_to_bf16_vec(const float4* __restrict__ in, uint2* __restrict__ out) {
  int idx = blockIdx.x * 256 + threadIdx.x;
  float4 v = in[idx];
  out[idx] = make_uint2(pack_bf2(v.x, v.y), pack_bf2(v.z, v.w));
}

// ---------------- GEMM (m97 structure, 128^2): C = A * Bt^T + bias ----------
// 1D grid + bijective XCD swizzle (T1). Requires gridDim.x % 8 == 0.
// R4 lesson: 256^2 tile WITHOUT the 8-phase counted-vmcnt schedule regresses.
#define BM 128
#define BN 128
#define BK 64

template <int OUT_F32, int NBX>
__global__ __launch_bounds__(256, 2) void gemm_bt(const u16* __restrict__ A,
                                                  const u16* __restrict__ Bt,
                                                  const float* __restrict__ bias,
                                                  void* __restrict__ Cout,
                                                  int M, int N, int K, int ldc,
                                                  int sc_lo, int sc_hi, float qs) {
  __shared__ __align__(16) u16 As[BM * BK];
  __shared__ __align__(16) u16 Bs[BN * BK];
  int id = blockIdx.x;
  int cpx = gridDim.x >> 3;
  int swz = (id & 7) * cpx + (id >> 3);
  int bn = (swz % NBX) * BN, bm = (swz / NBX) * BM;
  int tid = threadIdx.x;
  int wave = tid >> 6, lane = tid & 63;
  int quad = lane >> 4, l16 = lane & 15;
  int wm = (wave >> 1) * 64, wn = (wave & 1) * 64;

  f32x4 acc[4][4] = {};

  int lrow = lane >> 3, lcol = (lane & 7) * 8;
  const u16* gA = A + (size_t)(bm + wave * 8 + lrow) * K + lcol;
  const u16* gB = Bt + (size_t)(bn + wave * 8 + lrow) * K + lcol;
  u16* lA = &As[wave * 8 * BK];
  u16* lB = &Bs[wave * 8 * BK];

  for (int k0 = 0; k0 < K; k0 += BK) {
#pragma unroll
    for (int p = 0; p < 4; ++p) {
      ASYNC16(gA + (size_t)p * 32 * K, lA + p * 32 * BK);
      ASYNC16(gB + (size_t)p * 32 * K, lB + p * 32 * BK);
    }
    gA += BK;
    gB += BK;
    __syncthreads();
#pragma unroll
    for (int kk = 0; kk < BK; kk += 32) {
      bf16x8 af[4], bfr[4];
#pragma unroll
      for (int i = 0; i < 4; ++i)
        af[i] = *(const bf16x8*)&As[(wm + 16 * i + l16) * BK + kk + quad * 8];
#pragma unroll
      for (int j = 0; j < 4; ++j)
        bfr[j] = *(const bf16x8*)&Bs[(wn + 16 * j + l16) * BK + kk + quad * 8];
#pragma unroll
      for (int i = 0; i < 4; ++i)
#pragma unroll
        for (int j = 0; j < 4; ++j)
          acc[i][j] = MFMA(af[i], bfr[j], acc[i][j]);
    }
    __syncthreads();
  }

#pragma unroll
  for (int i = 0; i < 4; ++i) {
#pragma unroll
    for (int j = 0; j < 4; ++j) {
      int gn = bn + wn + 16 * j + l16;
      float bv = bias[gn];
      float sc = (gn >= sc_lo && gn < sc_hi) ? qs : 1.0f;
#pragma unroll
      for (int r = 0; r < 4; ++r) {
        int gm = bm + wm + 16 * i + quad * 4 + r;
        float v = (acc[i][j][r] + bv) * sc;
        if (OUT_F32)
          ((float*)Cout)[(size_t)gm * ldc + gn] = v;
        else
          ((u16*)Cout)[(size_t)gm * ldc + gn] = f2bf(v);
      }
    }
  }
}

#define SEQ 2048
#define ROWS3 3072

// ---------------- V transpose: kqv V-chunk -> vt[bh][d][s-perm] ----------------
// Within each 64-key tile, slot s holds key kappa(s) = s with bits 2<->3
// swapped (involution). Derivation: swapped 32x32 QK^T gives lane l the keys
// {(p&3)+8*(p>>2)+4*(l>>5)} per 32-block (bit2 == lane-half); PV's A-operand
// slot s is provided by lane-half (s>>3)&1; bit-2<->3 swap aligns the two and
// makes pa[m] = regs [8*(m&1)..+7] of score block jb=m>>1 -- contiguous.
__global__ void v_transpose(const u16* __restrict__ kqv, u16* __restrict__ vt) {
  int bh = blockIdx.y;
  int b = bh >> 4, h = bh & 15;
  int t0 = blockIdx.x * 64;
  int tid = threadIdx.x;
  __shared__ u16 tile[64][72];  // [k][d]
  int r = tid >> 3, c = (tid & 7) * 8;
#pragma unroll
  for (int p = 0; p < 2; ++p)
    *(uint4*)&tile[p * 32 + r][c] =
        *(const uint4*)&kqv[(size_t)b * SEQ * ROWS3 + (size_t)(t0 + p * 32 + r) * ROWS3 +
                            2048 + h * 64 + c];
  __syncthreads();
#pragma unroll
  for (int p = 0; p < 2; ++p) {
    int d = p * 32 + r;
    u16 tmp[8];
#pragma unroll
    for (int i = 0; i < 8; ++i) {
      int pos = c + i;
      int k = (pos & ~12) | ((pos & 8) >> 1) | ((pos & 4) << 1);  // swap bits 2,3
      tmp[i] = tile[k][d];
    }
    *(uint4*)&vt[(size_t)bh * 64 * SEQ + (size_t)d * SEQ + t0 + c] = *(uint4*)tmp;
  }
}

// ---------------- flash attention v11: 32x32x16 MFMA ----------------
// 256 thr = 4 waves x 32 q-rows; one wave = ONE 32-row MFMA tile.
// Instruction diet vs v9: 36 -> 20 MFMA per tile-wave at a ~13% faster
// per-FLOP pipe (m119: 2495 vs 2176 TF); exp/pack/ds_read unchanged.
// Swapped QK^T (mfma(K,Q)): lane l holds S[keys][q=l&31] -- all 32 scores
// are the lane's OWN q-row; row-sum accumulator ol matches o's reg index p
// exactly (both rows = crow(p,l)), so the epilogue divide is reg-local.
// PV slot->key map = bit-2<->3 swap, baked into v_transpose.
// Simple v9 2-buffer loop (R5's cross-tile pipeline measured null).
__global__ __launch_bounds__(256, 4) void attn_kernel(const u16* __restrict__ kqv,
                                                      const u16* __restrict__ vt,
                                                      u16* __restrict__ out) {
  int g = blockIdx.x;
  int bh = g & 63, qtile = g >> 6;
  int b = bh >> 4, h = bh & 15;
  int tid = threadIdx.x, wave = tid >> 6, lane = tid & 63;
  int l32 = lane & 31, half = lane >> 5;

  __shared__ __align__(16) u16 Ks[2][64 * 64];   // dbuf, interleaved 8-row blocks
  __shared__ __align__(16) u16 Vts[2][64 * 64];  // dbuf, interleaved

  const u16* base = kqv + (size_t)b * SEQ * ROWS3;
  int hcol = h * 64;
  const u16* vbase = vt + (size_t)bh * 64 * SEQ;

  // Q fragments (B-operand): lane l -> Q[qbase + l32][16*ds + 8*half + e]
  int qbase = qtile * 128 + wave * 32;
  bf16x8 qf[4];
  {
    const u16* qrow = base + (size_t)(qbase + l32) * ROWS3 + 1024 + hcol;  // Q_OFF=1024
#pragma unroll
    for (int ds = 0; ds < 4; ++ds) qf[ds] = *(const bf16x8*)(qrow + ds * 16 + half * 8);
  }

  bf16x8 ones;
#pragma unroll
  for (int i = 0; i < 8; ++i) ones[i] = (short)0x3F80;

  f32x16 o0 = {}, o1 = {}, ol = {};
  const f32x16 z16 = {};  // persistent zero C-operand

  // staging lane mapping: lane l -> row l&7, 16B-chunk l>>3 of an 8-row group
  int prow = lane & 7;
  int pchk = (lane >> 3) * 8;  // elems

  // fragment-read base (elems) into the interleaved layout:
  // row r, chunk c -> (r>>3)*512 + c*64 + (r&7)*8 ; here r = l32 (key or d-row),
  // c = 2*step + half  ->  base + step*128 (+2048 per 32-row block)
  int fb = (l32 >> 3) * 512 + half * 64 + (l32 & 7) * 8;

  // staging pointers, advanced incrementally
  const u16* kg = base + hcol + (size_t)(wave * 16 + prow) * ROWS3 + pchk;  // K_OFF=0
  const u16* vg = vbase + (size_t)(wave * 16 + prow) * SEQ + pchk;

  // prologue: stage tile 0 into buffer 0
  ASYNC16(kg, &Ks[0][wave * 16 * 64]);
  ASYNC16(kg + (size_t)8 * ROWS3, &Ks[0][(wave * 16 + 8) * 64]);
  ASYNC16(vg, &Vts[0][wave * 16 * 64]);
  ASYNC16(vg + (size_t)8 * SEQ, &Vts[0][(wave * 16 + 8) * 64]);

  int cur = 0;

  for (int t0 = 0; t0 < SEQ; t0 += 64) {
    // barrier: own prefetch (now [cur]) drained (vmcnt0); all waves done
    // reading [cur^1] from the previous iteration.
    __syncthreads();

    if (t0 + 64 < SEQ) {
      kg += (size_t)64 * ROWS3;
      vg += 64;
      ASYNC16(kg, &Ks[cur ^ 1][wave * 16 * 64]);
      ASYNC16(kg + (size_t)8 * ROWS3, &Ks[cur ^ 1][(wave * 16 + 8) * 64]);
      ASYNC16(vg, &Vts[cur ^ 1][wave * 16 * 64]);
      ASYNC16(vg + (size_t)8 * SEQ, &Vts[cur ^ 1][(wave * 16 + 8) * 64]);
    }

    const u16* ks = &Ks[cur][0];
    const u16* vs = &Vts[cur][0];

    __builtin_amdgcn_s_setprio(1);

    // Swapped QK^T, jb=0 (keys 0..31): S = sum_ds mfma32(K_frag, Q_frag)
    // K A-frag: lane l -> K[key=32jb+l32][d=16ds+8*half+e]  (Q pre-scaled)
    f32x16 s0, s1;
    {
      bf16x8 kf = *(const bf16x8*)&ks[fb];
      s0 = MFMA32(kf, qf[0], z16);
#pragma unroll
      for (int ds = 1; ds < 4; ++ds) {
        bf16x8 kf2 = *(const bf16x8*)&ks[fb + ds * 128];
        s0 = MFMA32(kf2, qf[ds], s0);
      }
    }
    // jb=1 (keys 32..63): +4 row-blocks = +2048 elems
    {
      bf16x8 kf = *(const bf16x8*)&ks[2048 + fb];
      s1 = MFMA32(kf, qf[0], z16);
#pragma unroll
      for (int ds = 1; ds < 4; ++ds) {
        bf16x8 kf2 = *(const bf16x8*)&ks[2048 + fb + ds * 128];
        s1 = MFMA32(kf2, qf[ds], s1);
      }
    }

    // exp2 + pack into PV A-fragments: pa[m] = regs [8*(m&1)..+7] of jb=m>>1
    bf16x8 pa[4];
    pa[0] = EXP_PACK8(s0, 0);
    pa[1] = EXP_PACK8(s0, 8);
    pa[2] = EXP_PACK8(s1, 0);
    pa[3] = EXP_PACK8(s1, 8);

    // PV + row-sum: V B-frag (m,do): lane l -> V[slot 16m+8*half+e][d=32do+l32]
#pragma unroll
    for (int m = 0; m < 4; ++m) {
      bf16x8 v0 = *(const bf16x8*)&vs[fb + m * 128];
      bf16x8 v1 = *(const bf16x8*)&vs[2048 + fb + m * 128];
      o0 = MFMA32(pa[m], v0, o0);
      o1 = MFMA32(pa[m], v1, o1);
      ol = MFMA32(pa[m], ones, ol);
    }

    __builtin_amdgcn_s_setprio(0);

    cur ^= 1;
  }

  // epilogue: lane l reg p holds O[q=crow(p,l)][d=32do+l32]; ol[p] = L[q] same p.
#pragma unroll
  for (int p = 0; p < 16; ++p) {
    float inv = 1.0f / ol[p];
    int q = (p & 3) + 8 * (p >> 2) + 4 * half;
    u16* orow = out + (size_t)(b * SEQ + qbase + q) * 1024 + hcol + l32;
    orow[0] = f2bf(o0[p] * inv);
    orow[32] = f2bf(o1[p] * inv);
  }
}

extern "C" void kernel_launch(void* const* d_in, const int* in_sizes, int n_in,
                              void* d_out, int out_size, void* d_ws, size_t ws_size,
                              hipStream_t stream) {
  const float* x     = (const float*)d_in[0];
  const float* w_in  = (const float*)d_in[1];
  const float* b_in  = (const float*)d_in[2];
  const float* w_out = (const float*)d_in[3];
  const float* b_out = (const float*)d_in[4];
  float* outp = (float*)d_out;

  char* p = (char*)d_ws;
  u16* wT_in  = (u16*)p; p += (size_t)3072 * 1024 * 2;
  u16* wT_out = (u16*)p; p += (size_t)1024 * 1024 * 2;
  u16* xb     = (u16*)p; p += (size_t)8192 * 1024 * 2;  // reused as vt after GEMM1
  u16* kqv    = (u16*)p; p += (size_t)8192 * 3072 * 2;
  u16* attn   = (u16*)p;
  u16* vtbuf  = xb;  // xb dead after GEMM1; vt is 64*64*2048 u16 = 16 MB

  transpose_to_bf16<<<dim3(3072 / 32, 1024 / 32), dim3(32, 8), 0, stream>>>(w_in, wT_in, 1024, 3072);
  transpose_to_bf16<<<dim3(1024 / 32, 1024 / 32), dim3(32, 8), 0, stream>>>(w_out, wT_out, 1024, 1024);
  f32_to_bf16_vec<<<dim3(8192), dim3(256), 0, stream>>>((const float4*)x, (uint2*)xb);

  const float QSCALE = 0.125f * 1.44269504088896f;
  gemm_bt<0, 3072 / BN><<<dim3((3072 / BN) * (8192 / BM)), 256, 0, stream>>>(
      xb, wT_in, b_in, (void*)kqv, 8192, 3072, 1024, 3072, 1024, 2048, QSCALE);

  v_transpose<<<dim3(SEQ / 64, 64), 256, 0, stream>>>(kqv, vtbuf);

  attn_kernel<<<dim3(1024), 256, 0, stream>>>(kqv, vtbuf, attn);

  gemm_bt<1, 1024 / BN><<<dim3((1024 / BN) * (8192 / BM)), 256, 0, stream>>>(
      attn, wT_out, b_out, (void*)outp, 8192, 1024, 1024, 1024, 0, 0, 1.0f);
}

// Round 7
// 280.000 us; speedup vs baseline: 1.0227x; 1.0227x over previous
//
#include <hip/hip_runtime.h>

typedef unsigned short u16;
typedef __attribute__((ext_vector_type(8))) short bf16x8;
typedef __attribute__((ext_vector_type(4))) float f32x4;

#define MFMA(a, b, c) __builtin_amdgcn_mfma_f32_16x16x32_bf16(a, b, c, 0, 0, 0)

// 2^x. clang builtin lowers to v_exp_f32 with compiler-managed TRANS hazards.
#if defined(__has_builtin)
#if __has_builtin(__builtin_amdgcn_exp2f)
#define EXP2(x) __builtin_amdgcn_exp2f(x)
#endif
#endif
#ifndef EXP2
#define EXP2(x) exp2f(x)
#endif

// async global->LDS, 16B per lane; lds ptr must be wave-uniform base.
#define ASYNC16(g, l)                                                      \
  __builtin_amdgcn_global_load_lds(                                        \
      (const __attribute__((address_space(1))) void*)(g),                  \
      (__attribute__((address_space(3))) void*)(l), 16, 0, 0)

__device__ __forceinline__ u16 f2bf(float x) {
  union { float f; unsigned u; } v; v.f = x;
  unsigned r = (v.u + 0x7fffu + ((v.u >> 16) & 1u)) >> 16;
  return (u16)r;
}

// pack two f32 -> bf16x2 (round-half-up), plain VALU ops (hazard-visible)
__device__ __forceinline__ unsigned pack_bf2(float a, float b) {
  unsigned ua = __float_as_uint(a) + 0x8000u;
  unsigned ub = __float_as_uint(b) + 0x8000u;
  return __builtin_amdgcn_perm(ub, ua, 0x07060302u);
}

// exp2 + pack 8 scores (two f32x4) into one bf16x8 A-fragment, in registers.
__device__ __forceinline__ bf16x8 exp_pack8(const f32x4 a, const f32x4 b) {
  union { unsigned u[4]; bf16x8 v; } r;
  r.u[0] = pack_bf2(EXP2(a[0]), EXP2(a[1]));
  r.u[1] = pack_bf2(EXP2(a[2]), EXP2(a[3]));
  r.u[2] = pack_bf2(EXP2(b[0]), EXP2(b[1]));
  r.u[3] = pack_bf2(EXP2(b[2]), EXP2(b[3]));
  return r.v;
}

// ---------------- fused preprocessing: both W transposes + x convert --------
// One kernel, block-uniform branch (no divergent __syncthreads):
//   blocks [0,3072)      : w_in  1024x3072 -> wT_in  (transpose + bf16)
//   blocks [3072,4096)   : w_out 1024x1024 -> wT_out
//   blocks [4096,12288)  : x fp32 -> xb bf16 (vectorized)
__global__ __launch_bounds__(256) void prep_fused(const float* __restrict__ w_in,
                                                  u16* __restrict__ wT_in,
                                                  const float* __restrict__ w_out,
                                                  u16* __restrict__ wT_out,
                                                  const float4* __restrict__ x,
                                                  uint2* __restrict__ xb) {
  int bid = blockIdx.x;
  int tid = threadIdx.x;
  if (bid >= 4096) {
    int idx = (bid - 4096) * 256 + tid;
    float4 v = x[idx];
    xb[idx] = make_uint2(pack_bf2(v.x, v.y), pack_bf2(v.z, v.w));
    return;
  }
  const float* in;
  u16* out;
  int R = 1024, C, bx, by;
  if (bid < 3072) {
    in = w_in; out = wT_in; C = 3072; bx = bid % 96; by = bid / 96;
  } else {
    int b2 = bid - 3072;
    in = w_out; out = wT_out; C = 1024; bx = b2 & 31; by = b2 >> 5;
  }
  __shared__ float tile[32][33];
  int tx = tid & 31, ty = tid >> 5;  // 32 x 8
  int c0 = bx * 32, r0 = by * 32;
#pragma unroll
  for (int i = 0; i < 32; i += 8)
    tile[ty + i][tx] = in[(size_t)(r0 + ty + i) * C + c0 + tx];
  __syncthreads();
#pragma unroll
  for (int i = 0; i < 32; i += 8)
    out[(size_t)(c0 + ty + i) * R + r0 + tx] = f2bf(tile[tx][ty + i]);
}

// ---------------- GEMM (m97 structure, 128^2): C = A * Bt^T + bias ----------
// 1D grid + bijective XCD swizzle (T1). Requires gridDim.x % 8 == 0.
// R4 lesson: 256^2 tile WITHOUT the 8-phase counted-vmcnt schedule regresses
// (1 block/CU, drain-bound, MfmaUtil 18%). 128^2 2-phase is the proven config.
#define BM 128
#define BN 128
#define BK 64

template <int OUT_F32, int NBX>
__global__ __launch_bounds__(256, 2) void gemm_bt(const u16* __restrict__ A,
                                                  const u16* __restrict__ Bt,
                                                  const float* __restrict__ bias,
                                                  void* __restrict__ Cout,
                                                  int M, int N, int K, int ldc,
                                                  int sc_lo, int sc_hi, float qs) {
  __shared__ __align__(16) u16 As[BM * BK];
  __shared__ __align__(16) u16 Bs[BN * BK];
  int id = blockIdx.x;
  int cpx = gridDim.x >> 3;
  int swz = (id & 7) * cpx + (id >> 3);
  int bn = (swz % NBX) * BN, bm = (swz / NBX) * BM;
  int tid = threadIdx.x;
  int wave = tid >> 6, lane = tid & 63;
  int quad = lane >> 4, l16 = lane & 15;
  int wm = (wave >> 1) * 64, wn = (wave & 1) * 64;

  f32x4 acc[4][4] = {};

  int lrow = lane >> 3, lcol = (lane & 7) * 8;
  const u16* gA = A + (size_t)(bm + wave * 8 + lrow) * K + lcol;
  const u16* gB = Bt + (size_t)(bn + wave * 8 + lrow) * K + lcol;
  u16* lA = &As[wave * 8 * BK];
  u16* lB = &Bs[wave * 8 * BK];

  for (int k0 = 0; k0 < K; k0 += BK) {
#pragma unroll
    for (int p = 0; p < 4; ++p) {
      ASYNC16(gA + (size_t)p * 32 * K, lA + p * 32 * BK);
      ASYNC16(gB + (size_t)p * 32 * K, lB + p * 32 * BK);
    }
    gA += BK;
    gB += BK;
    __syncthreads();
#pragma unroll
    for (int kk = 0; kk < BK; kk += 32) {
      bf16x8 af[4], bfr[4];
#pragma unroll
      for (int i = 0; i < 4; ++i)
        af[i] = *(const bf16x8*)&As[(wm + 16 * i + l16) * BK + kk + quad * 8];
#pragma unroll
      for (int j = 0; j < 4; ++j)
        bfr[j] = *(const bf16x8*)&Bs[(wn + 16 * j + l16) * BK + kk + quad * 8];
#pragma unroll
      for (int i = 0; i < 4; ++i)
#pragma unroll
        for (int j = 0; j < 4; ++j)
          acc[i][j] = MFMA(af[i], bfr[j], acc[i][j]);
    }
    __syncthreads();
  }

#pragma unroll
  for (int i = 0; i < 4; ++i) {
#pragma unroll
    for (int j = 0; j < 4; ++j) {
      int gn = bn + wn + 16 * j + l16;
      float bv = bias[gn];
      float sc = (gn >= sc_lo && gn < sc_hi) ? qs : 1.0f;
#pragma unroll
      for (int r = 0; r < 4; ++r) {
        int gm = bm + wm + 16 * i + quad * 4 + r;
        float v = (acc[i][j][r] + bv) * sc;
        if (OUT_F32)
          ((float*)Cout)[(size_t)gm * ldc + gn] = v;
        else
          ((u16*)Cout)[(size_t)gm * ldc + gn] = f2bf(v);
      }
    }
  }
}

#define SEQ 2048
#define ROWS3 3072

// ---------------- V transpose: kqv V-chunk -> vt[bh][d][s-perm] ----------------
// Within each 64-key tile, slot s holds key kappa(s) chosen so the attention
// kernel's in-register P fragments (swapped QK^T: lane quad holds keys
// 16j+quad*4+r) contract against V with NO cross-lane movement:
//   kappa(s) = 16*(2*(s>>5) + ((s>>2)&1)) + ((s>>3)&3)*4 + (s&3)
__global__ void v_transpose(const u16* __restrict__ kqv, u16* __restrict__ vt) {
  int bh = blockIdx.y;
  int b = bh >> 4, h = bh & 15;
  int t0 = blockIdx.x * 64;
  int tid = threadIdx.x;
  __shared__ u16 tile[64][72];  // [k][d]
  int r = tid >> 3, c = (tid & 7) * 8;
#pragma unroll
  for (int p = 0; p < 2; ++p)
    *(uint4*)&tile[p * 32 + r][c] =
        *(const uint4*)&kqv[(size_t)b * SEQ * ROWS3 + (size_t)(t0 + p * 32 + r) * ROWS3 +
                            2048 + h * 64 + c];
  __syncthreads();
#pragma unroll
  for (int p = 0; p < 2; ++p) {
    int d = p * 32 + r;
    u16 tmp[8];
#pragma unroll
    for (int i = 0; i < 8; ++i) {
      int pos = c + i;
      int k = 16 * (2 * (pos >> 5) + ((pos >> 2) & 1)) + ((pos >> 3) & 3) * 4 + (pos & 3);
      tmp[i] = tile[k][d];
    }
    *(uint4*)&vt[(size_t)bh * 64 * SEQ + (size_t)d * SEQ + t0 + c] = *(uint4*)tmp;
  }
}

// ---------------- flash attention v10: cross-tile pipeline ----------------
// (measured best: 90.6-92.0 us, zero bank conflicts — R5)
// 256 thr = 4 waves x 32 q-rows. Swapped QK^T (mfma(K,Q)) -> P lane-local,
// in-register exp/pack into PV A-fragments (kappa baked into v_transpose).
// 2-tile software pipeline: iter t computes QK^T(t+1)+exp(t+1), PV(t) with
// previous tile's P. K double-buffered, V triple-buffered; 40 KiB LDS.
// R6 lesson: 32x32 MFMA variant has deterministic +4cyc/ds_read bank
// conflicts (8.4M/dispatch) — 16x16 fragment reads measure conflict-free.
__global__ __launch_bounds__(256, 4) void attn_kernel(const u16* __restrict__ kqv,
                                                      const u16* __restrict__ vt,
                                                      u16* __restrict__ out) {
  int g = blockIdx.x;
  int bh = g & 63, qtile = g >> 6;
  int b = bh >> 4, h = bh & 15;
  int tid = threadIdx.x, wave = tid >> 6, lane = tid & 63;
  int quad = lane >> 4, l16 = lane & 15;

  __shared__ __align__(16) u16 Ks[2][64 * 64];   // dbuf, interleaved 8-row blocks
  __shared__ __align__(16) u16 Vts[3][64 * 64];  // tribuf, interleaved

  const u16* base = kqv + (size_t)b * SEQ * ROWS3;
  int hcol = h * 64;
  const u16* vbase = vt + (size_t)bh * 64 * SEQ;

  // Q fragments: wave owns 32 q-rows = 2 MFMA row-tiles, resident
  bf16x8 qf[2][2];
#pragma unroll
  for (int t = 0; t < 2; ++t) {
    int s = qtile * 128 + wave * 32 + t * 16 + l16;
    const u16* qrow = base + (size_t)s * ROWS3 + 1024 + hcol;  // Q_OFF=1024
    qf[t][0] = *(const bf16x8*)(qrow + quad * 8);
    qf[t][1] = *(const bf16x8*)(qrow + 32 + quad * 8);
  }

  bf16x8 ones;
#pragma unroll
  for (int i = 0; i < 8; ++i) ones[i] = (short)0x3F80;

  f32x4 o[2][4] = {};
  f32x4 ol[2] = {};
  const f32x4 zf = {};  // persistent zero C-operand

  // staging lane mapping: lane l -> row l&7, 16B-chunk l>>3 of an 8-row group
  int prow = lane & 7;
  int pchk = (lane >> 3) * 8;  // elems

  // fragment-read addressing into the interleaved layout
  int rb2 = (l16 >> 3) * 512;  // 8-row sub-block offset (elems)
  int r8 = (l16 & 7) * 8;      // row-within-block offset (elems)

  // staging pointers: advance monotonically, one step per staged tile
  const u16* kg = base + hcol + (size_t)(wave * 16 + prow) * ROWS3 + pchk;
  const u16* vg = vbase + (size_t)(wave * 16 + prow) * SEQ + pchk;

#define STAGE_K(bi)                                      \
  do {                                                   \
    ASYNC16(kg, &Ks[bi][wave * 16 * 64]);                \
    ASYNC16(kg + (size_t)8 * ROWS3, &Ks[bi][(wave * 16 + 8) * 64]); \
    kg += (size_t)64 * ROWS3;                            \
  } while (0)
#define STAGE_V(bi)                                      \
  do {                                                   \
    ASYNC16(vg, &Vts[bi][wave * 16 * 64]);               \
    ASYNC16(vg + (size_t)8 * SEQ, &Vts[bi][(wave * 16 + 8) * 64]); \
    vg += 64;                                            \
  } while (0)

  const int NT = SEQ / 64;  // 32

  // prologue: tile 0 staged+drained; tile 1 in flight; QK^T(0)+exp -> pa
  STAGE_K(0);
  STAGE_V(0);
  __syncthreads();
  STAGE_K(1);
  STAGE_V(1);

  bf16x8 pa00, pa01, pa10, pa11;
  {
    const u16* ks = &Ks[0][0];
    f32x4 s0[4], s1[4];
#pragma unroll
    for (int j = 0; j < 4; ++j) {
      bf16x8 k0 = *(const bf16x8*)&ks[j * 1024 + rb2 + quad * 64 + r8];
      bf16x8 k1 = *(const bf16x8*)&ks[j * 1024 + rb2 + 256 + quad * 64 + r8];
      s0[j] = MFMA(k0, qf[0][0], zf);
      s0[j] = MFMA(k1, qf[0][1], s0[j]);
      s1[j] = MFMA(k0, qf[1][0], zf);
      s1[j] = MFMA(k1, qf[1][1], s1[j]);
    }
    pa00 = exp_pack8(s0[0], s0[1]);
    pa01 = exp_pack8(s0[2], s0[3]);
    pa10 = exp_pack8(s1[0], s1[1]);
    pa11 = exp_pack8(s1[2], s1[3]);
  }

  int v_rd = 0;  // Vts index holding V[t]
  int v_st = 2;  // Vts index receiving V[t+2]

  for (int t = 0; t < NT - 1; ++t) {
    // drains stage(t+1); fences all waves' reads of K[t] and V[t-1]
    __syncthreads();

    if (t + 2 < NT) {
      STAGE_K(t & 1);
      STAGE_V(v_st);
    }

    const u16* ks = &Ks[(t + 1) & 1][0];
    const u16* vs = &Vts[v_rd][0];

    __builtin_amdgcn_s_setprio(1);

    // QK^T(t+1): s[j] = mfma(K_j, Q_t); lane reg r = P[key=16j+quad*4+r][q=l16]
    f32x4 s0[4], s1[4];
#pragma unroll
    for (int j = 0; j < 4; ++j) {
      bf16x8 k0 = *(const bf16x8*)&ks[j * 1024 + rb2 + quad * 64 + r8];
      bf16x8 k1 = *(const bf16x8*)&ks[j * 1024 + rb2 + 256 + quad * 64 + r8];
      s0[j] = MFMA(k0, qf[0][0], zf);
      s0[j] = MFMA(k1, qf[0][1], s0[j]);
      s1[j] = MFMA(k0, qf[1][0], zf);
      s1[j] = MFMA(k1, qf[1][1], s1[j]);
    }

    // exp(t+1) -> next P-fragments (independent of PV below)
    bf16x8 pn00 = exp_pack8(s0[0], s0[1]);
    bf16x8 pn01 = exp_pack8(s0[2], s0[3]);
    bf16x8 pn10 = exp_pack8(s1[0], s1[1]);
    bf16x8 pn11 = exp_pack8(s1[2], s1[3]);

    // PV(t) with the PREVIOUS tile's pa: each V fragment read once.
#pragma unroll
    for (int d = 0; d < 4; ++d) {
      bf16x8 v0 = *(const bf16x8*)&vs[d * 1024 + rb2 + quad * 64 + r8];
      bf16x8 v1 = *(const bf16x8*)&vs[d * 1024 + rb2 + 256 + quad * 64 + r8];
      o[0][d] = MFMA(pa00, v0, o[0][d]);
      o[0][d] = MFMA(pa01, v1, o[0][d]);
      o[1][d] = MFMA(pa10, v0, o[1][d]);
      o[1][d] = MFMA(pa11, v1, o[1][d]);
    }
    ol[0] = MFMA(pa00, ones, ol[0]);
    ol[0] = MFMA(pa01, ones, ol[0]);
    ol[1] = MFMA(pa10, ones, ol[1]);
    ol[1] = MFMA(pa11, ones, ol[1]);

    __builtin_amdgcn_s_setprio(0);

    pa00 = pn00; pa01 = pn01; pa10 = pn10; pa11 = pn11;
    v_rd = (v_rd == 2) ? 0 : v_rd + 1;
    v_st = (v_st == 2) ? 0 : v_st + 1;
  }

  // peeled final tile: PV(NT-1) only (no further QK^T / staging in flight)
  __syncthreads();
  {
    const u16* vs = &Vts[v_rd][0];
    __builtin_amdgcn_s_setprio(1);
#pragma unroll
    for (int d = 0; d < 4; ++d) {
      bf16x8 v0 = *(const bf16x8*)&vs[d * 1024 + rb2 + quad * 64 + r8];
      bf16x8 v1 = *(const bf16x8*)&vs[d * 1024 + rb2 + 256 + quad * 64 + r8];
      o[0][d] = MFMA(pa00, v0, o[0][d]);
      o[0][d] = MFMA(pa01, v1, o[0][d]);
      o[1][d] = MFMA(pa10, v0, o[1][d]);
      o[1][d] = MFMA(pa11, v1, o[1][d]);
    }
    ol[0] = MFMA(pa00, ones, ol[0]);
    ol[0] = MFMA(pa01, ones, ol[0]);
    ol[1] = MFMA(pa10, ones, ol[1]);
    ol[1] = MFMA(pa11, ones, ol[1]);
    __builtin_amdgcn_s_setprio(0);
  }

  // epilogue: O /= l, merge heads
#pragma unroll
  for (int t = 0; t < 2; ++t)
#pragma unroll
    for (int r = 0; r < 4; ++r) {
      float inv = 1.0f / ol[t][r];
      int s = qtile * 128 + wave * 32 + t * 16 + quad * 4 + r;
      u16* orow = out + (size_t)(b * SEQ + s) * 1024 + hcol;
#pragma unroll
      for (int d = 0; d < 4; ++d) orow[16 * d + l16] = f2bf(o[t][d][r] * inv);
    }
#undef STAGE_K
#undef STAGE_V
}

extern "C" void kernel_launch(void* const* d_in, const int* in_sizes, int n_in,
                              void* d_out, int out_size, void* d_ws, size_t ws_size,
                              hipStream_t stream) {
  const float* x     = (const float*)d_in[0];
  const float* w_in  = (const float*)d_in[1];
  const float* b_in  = (const float*)d_in[2];
  const float* w_out = (const float*)d_in[3];
  const float* b_out = (const float*)d_in[4];
  float* outp = (float*)d_out;

  char* p = (char*)d_ws;
  u16* wT_in  = (u16*)p; p += (size_t)3072 * 1024 * 2;
  u16* wT_out = (u16*)p; p += (size_t)1024 * 1024 * 2;
  u16* xb     = (u16*)p; p += (size_t)8192 * 1024 * 2;  // reused as vt after GEMM1
  u16* kqv    = (u16*)p; p += (size_t)8192 * 3072 * 2;
  u16* attn   = (u16*)p;
  u16* vtbuf  = xb;  // xb dead after GEMM1; vt is 64*64*2048 u16 = 16 MB

  prep_fused<<<dim3(12288), dim3(256), 0, stream>>>(
      w_in, wT_in, w_out, wT_out, (const float4*)x, (uint2*)xb);

  const float QSCALE = 0.125f * 1.44269504088896f;
  gemm_bt<0, 3072 / BN><<<dim3((3072 / BN) * (8192 / BM)), 256, 0, stream>>>(
      xb, wT_in, b_in, (void*)kqv, 8192, 3072, 1024, 3072, 1024, 2048, QSCALE);

  v_transpose<<<dim3(SEQ / 64, 64), 256, 0, stream>>>(kqv, vtbuf);

  attn_kernel<<<dim3(1024), 256, 0, stream>>>(kqv, vtbuf, attn);

  gemm_bt<1, 1024 / BN><<<dim3((1024 / BN) * (8192 / BM)), 256, 0, stream>>>(
      attn, wT_out, b_out, (void*)outp, 8192, 1024, 1024, 1024, 0, 0, 1.0f);
}